// Round 1
// baseline (349.856 us; speedup 1.0000x reference)
//
#include <hip/hip_runtime.h>
#include <cstddef>

#define G_N   10000
#define L_N   1000
#define NSTA  400
#define NSRC  2000
#define KK    15

__device__ __forceinline__ float tr1k(float x) {
    // matches reference: _ftrns(x)/1000.0 = (x*1000.0f)/1000.0f with f32 rounding
    return (x * 1000.0f) / 1000.0f;
}

__device__ __forceinline__ float softplus(float x) {
    // jax.nn.softplus(x) = logaddexp(x, 0), stable form
    return fmaxf(x, 0.0f) + log1pf(expf(-fabsf(x)));
}

__device__ __forceinline__ bool lexless(float v1, int i1, float v2, int i2) {
    return (v1 < v2) || (v1 == v2 && i1 < i2);
}

// ---------------------------------------------------------------------------
// Kernel 1: sta_ind[i] = argmin_j ||tr(sta[i]) - tr(locs_ref[j])||^2
// one wave per station
// ---------------------------------------------------------------------------
__global__ void sta_ind_kernel(const float* __restrict__ sta,
                               const float* __restrict__ locs_ref,
                               int* __restrict__ sta_ind) {
#pragma clang fp contract(off)
    const int i    = blockIdx.x;
    const int lane = threadIdx.x;
    const float sx = tr1k(sta[i * 3 + 0]);
    const float sy = tr1k(sta[i * 3 + 1]);
    const float sz = tr1k(sta[i * 3 + 2]);
    float best = INFINITY;
    int   bidx = 0x7fffffff;
    for (int j = lane; j < L_N; j += 64) {
        float dx = sx - tr1k(locs_ref[j * 3 + 0]);
        float dy = sy - tr1k(locs_ref[j * 3 + 1]);
        float dz = sz - tr1k(locs_ref[j * 3 + 2]);
        float d  = (dx * dx + dy * dy) + dz * dz;
        if (lexless(d, j, best, bidx)) { best = d; bidx = j; }
    }
    for (int off = 1; off < 64; off <<= 1) {
        float ov = __shfl_xor(best, off);
        int   oi = __shfl_xor(bidx, off);
        if (lexless(ov, oi, best, bidx)) { best = ov; bidx = oi; }
    }
    if (lane == 0) sta_ind[i] = bidx;
}

// ---------------------------------------------------------------------------
// Kernel 2: per src s, indices of the K smallest dq[s,g] = ||tr(src)-tr(grid)||^2
// sorted ascending by (dq, g) -- matches jax.lax.top_k(-dq, K) semantics.
// one wave per src; per-lane register top-K list + wave min-extract rounds.
// ---------------------------------------------------------------------------
__global__ void topk_kernel(const float* __restrict__ src,
                            const float* __restrict__ x_grid,
                            int* __restrict__ idx_out) {
#pragma clang fp contract(off)
    const int s    = blockIdx.x;
    const int lane = threadIdx.x;
    const float sx = tr1k(src[s * 3 + 0]);
    const float sy = tr1k(src[s * 3 + 1]);
    const float sz = tr1k(src[s * 3 + 2]);

    float vals[KK];
    int   ids[KK];
#pragma unroll
    for (int j = 0; j < KK; ++j) { vals[j] = INFINITY; ids[j] = 0x7fffffff; }

    for (int g = lane; g < G_N; g += 64) {
        float dx = sx - tr1k(x_grid[g * 3 + 0]);
        float dy = sy - tr1k(x_grid[g * 3 + 1]);
        float dz = sz - tr1k(x_grid[g * 3 + 2]);
        float d  = (dx * dx + dy * dy) + dz * dz;
        if (lexless(d, g, vals[KK - 1], ids[KK - 1])) {
            float cv = d; int ci = g;
#pragma unroll
            for (int j = 0; j < KK; ++j) {
                bool sw = lexless(cv, ci, vals[j], ids[j]);
                float tv = sw ? vals[j] : cv;
                int   ti = sw ? ids[j]  : ci;
                vals[j]  = sw ? cv : vals[j];
                ids[j]   = sw ? ci : ids[j];
                cv = tv; ci = ti;
            }
        }
    }

    // 15 rounds: extract global wave min (lexicographic), winner pops its head
    for (int r = 0; r < KK; ++r) {
        float v  = vals[0];
        int   id = ids[0];
        int   who = lane;
        for (int off = 1; off < 64; off <<= 1) {
            float ov = __shfl_xor(v, off);
            int   oi = __shfl_xor(id, off);
            int   ow = __shfl_xor(who, off);
            if (lexless(ov, oi, v, id)) { v = ov; id = oi; who = ow; }
        }
        if (lane == 0) idx_out[s * KK + r] = id;
        if (who == lane) {
#pragma unroll
            for (int j = 0; j < KK - 1; ++j) { vals[j] = vals[j + 1]; ids[j] = ids[j + 1]; }
            vals[KK - 1] = INFINITY;
            ids[KK - 1]  = 0x7fffffff;
        }
    }
}

// ---------------------------------------------------------------------------
// Kernel 3: main fused computation. One block per src, threads over stations.
// ---------------------------------------------------------------------------
__global__ __launch_bounds__(256) void magnitude_kernel(
    const float* __restrict__ sta, const float* __restrict__ src,
    const float* __restrict__ mag, const int* __restrict__ phase,
    const float* __restrict__ x_grid,
    const float* __restrict__ mag_coef, const float* __restrict__ epi_coef,
    const float* __restrict__ dep_coef,
    const float* __restrict__ coefs, const float* __restrict__ coefs_ker,
    const int* __restrict__ sta_ind, const int* __restrict__ idx,
    float* __restrict__ out)
{
    const int s   = blockIdx.x;
    const int tid = threadIdx.x;

    __shared__ float s_diff[KK][3];
    __shared__ int   s_g[KK];
    __shared__ int   s_sta[NSTA];

    if (tid < KK) {
        int g = idx[s * KK + tid];
        s_g[tid] = g;
        s_diff[tid][0] = tr1k(x_grid[g * 3 + 0]) - tr1k(src[s * 3 + 0]);
        s_diff[tid][1] = tr1k(x_grid[g * 3 + 1]) - tr1k(src[s * 3 + 1]);
        s_diff[tid][2] = tr1k(x_grid[g * 3 + 2]) - tr1k(src[s * 3 + 2]);
    }
    for (int i = tid; i < NSTA; i += 256) s_sta[i] = sta_ind[i];
    __syncthreads();

    const float mag_s = mag[s];
    const float srcx = src[s * 3 + 0];
    const float srcy = src[s * 3 + 1];
    const float srcz = src[s * 3 + 2];
    const float sp_mc0 = softplus(mag_coef[0]), sp_mc1 = softplus(mag_coef[1]);
    const float sp_ec0 = softplus(epi_coef[0]), sp_ec1 = softplus(epi_coef[1]);
    const float dc0 = dep_coef[0], dc1 = dep_coef[1];

    for (int i = tid; i < NSTA; i += 256) {
        const int st = s_sta[i];
        float wsum = 0.0f, a0 = 0.0f, a1 = 0.0f;
#pragma unroll
        for (int k = 0; k < KK; ++k) {
            const int g = s_g[k];
            const float* kp = coefs_ker + ((size_t)g * L_N + st) * 3;
            float k0 = softplus(kp[0]);
            float k1 = softplus(kp[1]);
            float k2 = softplus(kp[2]);
            float t0 = s_diff[k][0] / k0;
            float t1 = s_diff[k][1] / k1;
            float t2 = s_diff[k][2] / k2;
            float e  = expf(-0.5f * ((t0 * t0 + t1 * t1) + t2 * t2));
            const float* cp = coefs + ((size_t)g * L_N + st) * 2;
            wsum += e;
            a0 += e * cp[0];
            a1 += e * cp[1];
        }
        if (wsum == 0.0f) wsum = 1.0f;

        const int ph = phase[i];
        float bias = ((ph == 0) ? a0 : a1) / wsum;

        float dx = srcx * 1000.0f - sta[i * 3 + 0] * 1000.0f;
        float dy = srcy * 1000.0f - sta[i * 3 + 1] * 1000.0f;
        float lz = log10f(sqrtf(dx * dx + dy * dy) + 1.0f);
        float ld = log10f(fabsf(srcz - sta[i * 3 + 2]) + 1.0f);

        float mc = (ph == 0) ? sp_mc0 : sp_mc1;
        float ec = (ph == 0) ? sp_ec0 : sp_ec1;
        float dc = (ph == 0) ? dc0 : dc1;

        out[(size_t)s * NSTA + i] = mag_s * mc - ec * lz + dc * ld + bias;
    }
}

extern "C" void kernel_launch(void* const* d_in, const int* in_sizes, int n_in,
                              void* d_out, int out_size, void* d_ws, size_t ws_size,
                              hipStream_t stream) {
    const float* sta       = (const float*)d_in[0];
    const float* src       = (const float*)d_in[1];
    const float* mag       = (const float*)d_in[2];
    const int*   phase     = (const int*)d_in[3];
    const float* x_grid    = (const float*)d_in[4];
    const float* locs_ref  = (const float*)d_in[5];
    const float* mag_coef  = (const float*)d_in[6];
    const float* epi_coef  = (const float*)d_in[7];
    const float* dep_coef  = (const float*)d_in[8];
    const float* coefs     = (const float*)d_in[9];
    const float* coefs_ker = (const float*)d_in[10];
    float* out = (float*)d_out;

    int* ws_sta_ind = (int*)d_ws;
    int* ws_idx     = ws_sta_ind + NSTA;

    hipLaunchKernelGGL(sta_ind_kernel, dim3(NSTA), dim3(64), 0, stream,
                       sta, locs_ref, ws_sta_ind);
    hipLaunchKernelGGL(topk_kernel, dim3(NSRC), dim3(64), 0, stream,
                       src, x_grid, ws_idx);
    hipLaunchKernelGGL(magnitude_kernel, dim3(NSRC), dim3(256), 0, stream,
                       sta, src, mag, phase, x_grid,
                       mag_coef, epi_coef, dep_coef,
                       coefs, coefs_ker, ws_sta_ind, ws_idx, out);
}

// Round 2
// 229.626 us; speedup vs baseline: 1.5236x; 1.5236x over previous
//
#include <hip/hip_runtime.h>
#include <cstddef>

#define G_N   10000
#define L_N   1000
#define NSTA  400
#define NSRC  2000
#define KK    15

__device__ __forceinline__ float tr1k(float x) {
    // matches reference: _ftrns(x)/1000.0 = (x*1000.0f)/1000.0f with f32 rounding
    return (x * 1000.0f) / 1000.0f;
}

__device__ __forceinline__ float softplus(float x) {
    // jax.nn.softplus(x) = logaddexp(x, 0), stable form
    return fmaxf(x, 0.0f) + log1pf(expf(-fabsf(x)));
}

__device__ __forceinline__ bool lexless(float v1, int i1, float v2, int i2) {
    return (v1 < v2) || (v1 == v2 && i1 < i2);
}

// ---------------------------------------------------------------------------
// Kernel 1: sta_ind[i] = argmin_j ||tr(sta[i]) - tr(locs_ref[j])||^2
// one wave per station
// ---------------------------------------------------------------------------
__global__ void sta_ind_kernel(const float* __restrict__ sta,
                               const float* __restrict__ locs_ref,
                               int* __restrict__ sta_ind) {
#pragma clang fp contract(off)
    const int i    = blockIdx.x;
    const int lane = threadIdx.x;
    const float sx = tr1k(sta[i * 3 + 0]);
    const float sy = tr1k(sta[i * 3 + 1]);
    const float sz = tr1k(sta[i * 3 + 2]);
    float best = INFINITY;
    int   bidx = 0x7fffffff;
    for (int j = lane; j < L_N; j += 64) {
        float dx = sx - tr1k(locs_ref[j * 3 + 0]);
        float dy = sy - tr1k(locs_ref[j * 3 + 1]);
        float dz = sz - tr1k(locs_ref[j * 3 + 2]);
        float d  = (dx * dx + dy * dy) + dz * dz;
        if (lexless(d, j, best, bidx)) { best = d; bidx = j; }
    }
    for (int off = 1; off < 64; off <<= 1) {
        float ov = __shfl_xor(best, off);
        int   oi = __shfl_xor(bidx, off);
        if (lexless(ov, oi, best, bidx)) { best = ov; bidx = oi; }
    }
    if (lane == 0) sta_ind[i] = bidx;
}

// ---------------------------------------------------------------------------
// Kernel 2: per src s, indices of the K smallest dq[s,g], ascending by (dq,g).
// 256 threads/block; per-thread register top-K over ~40 candidates,
// per-wave 15-round lex-min extraction, then cross-wave merge in LDS.
// ---------------------------------------------------------------------------
__global__ __launch_bounds__(256) void topk_kernel(const float* __restrict__ src,
                                                   const float* __restrict__ x_grid,
                                                   int* __restrict__ idx_out) {
#pragma clang fp contract(off)
    const int s    = blockIdx.x;
    const int tid  = threadIdx.x;
    const int lane = tid & 63;
    const int wv   = tid >> 6;
    const float sx = tr1k(src[s * 3 + 0]);
    const float sy = tr1k(src[s * 3 + 1]);
    const float sz = tr1k(src[s * 3 + 2]);

    float vals[KK];
    int   ids[KK];
#pragma unroll
    for (int j = 0; j < KK; ++j) { vals[j] = INFINITY; ids[j] = 0x7fffffff; }

    for (int g = tid; g < G_N; g += 256) {
        float dx = sx - tr1k(x_grid[g * 3 + 0]);
        float dy = sy - tr1k(x_grid[g * 3 + 1]);
        float dz = sz - tr1k(x_grid[g * 3 + 2]);
        float d  = (dx * dx + dy * dy) + dz * dz;
        if (lexless(d, g, vals[KK - 1], ids[KK - 1])) {
            float cv = d; int ci = g;
#pragma unroll
            for (int j = 0; j < KK; ++j) {
                bool sw = lexless(cv, ci, vals[j], ids[j]);
                float tv = sw ? vals[j] : cv;
                int   ti = sw ? ids[j]  : ci;
                vals[j]  = sw ? cv : vals[j];
                ids[j]   = sw ? ci : ids[j];
                cv = tv; ci = ti;
            }
        }
    }

    __shared__ float l_v[4 * KK];
    __shared__ int   l_i[4 * KK];

    // per-wave: extract its sorted top-15 into LDS
    for (int r = 0; r < KK; ++r) {
        float v  = vals[0];
        int   id = ids[0];
        int   who = lane;
        for (int off = 1; off < 64; off <<= 1) {
            float ov = __shfl_xor(v, off);
            int   oi = __shfl_xor(id, off);
            int   ow = __shfl_xor(who, off);
            if (lexless(ov, oi, v, id)) { v = ov; id = oi; who = ow; }
        }
        if (lane == 0) { l_v[wv * KK + r] = v; l_i[wv * KK + r] = id; }
        if (who == lane) {
#pragma unroll
            for (int j = 0; j < KK - 1; ++j) { vals[j] = vals[j + 1]; ids[j] = ids[j + 1]; }
            vals[KK - 1] = INFINITY;
            ids[KK - 1]  = 0x7fffffff;
        }
    }
    __syncthreads();

    // wave 0: merge the 60 candidates
    if (wv == 0) {
        float v  = (lane < 4 * KK) ? l_v[lane] : INFINITY;
        int   id = (lane < 4 * KK) ? l_i[lane] : 0x7fffffff;
        for (int r = 0; r < KK; ++r) {
            float mv = v; int mi = id; int who = lane;
            for (int off = 1; off < 64; off <<= 1) {
                float ov = __shfl_xor(mv, off);
                int   oi = __shfl_xor(mi, off);
                int   ow = __shfl_xor(who, off);
                if (lexless(ov, oi, mv, mi)) { mv = ov; mi = oi; who = ow; }
            }
            if (lane == 0) idx_out[s * KK + r] = mi;
            if (who == lane) { v = INFINITY; id = 0x7fffffff; }
        }
    }
}

// ---------------------------------------------------------------------------
// Kernel 3: pack. One block per grid point g. Stages the full ker/coef rows
// in LDS (coalesced), gathers the 400 station columns, folds softplus ->
// reciprocal and the per-station phase select, writes float4 [g][i].
// ---------------------------------------------------------------------------
__global__ __launch_bounds__(256) void pack_kernel(
    const float* __restrict__ coefs, const float* __restrict__ coefs_ker,
    const int* __restrict__ sta_ind, const int* __restrict__ phase,
    float4* __restrict__ pk)
{
    const int g   = blockIdx.x;
    const int tid = threadIdx.x;
    __shared__ float s_ker[L_N * 3];
    __shared__ float s_c[L_N * 2];
    __shared__ int   s_sta[NSTA];
    __shared__ int   s_ph[NSTA];

    const float* kerrow = coefs_ker + (size_t)g * L_N * 3;
    const float* crow   = coefs + (size_t)g * L_N * 2;
    for (int j = tid; j < L_N * 3; j += 256) s_ker[j] = kerrow[j];
    for (int j = tid; j < L_N * 2; j += 256) s_c[j] = crow[j];
    for (int j = tid; j < NSTA; j += 256) { s_sta[j] = sta_ind[j]; s_ph[j] = phase[j]; }
    __syncthreads();

    for (int i = tid; i < NSTA; i += 256) {
        const int st = s_sta[i];
        float rk0 = 1.0f / softplus(s_ker[st * 3 + 0]);
        float rk1 = 1.0f / softplus(s_ker[st * 3 + 1]);
        float rk2 = 1.0f / softplus(s_ker[st * 3 + 2]);
        float c   = (s_ph[i] == 0) ? s_c[st * 2 + 0] : s_c[st * 2 + 1];
        pk[(size_t)g * NSTA + i] = make_float4(rk0, rk1, rk2, c);
    }
}

// ---------------------------------------------------------------------------
// Kernel 4: main fused computation, fast path. Block per src, coalesced
// float4 reads of the packed table.
// ---------------------------------------------------------------------------
__global__ __launch_bounds__(256) void magnitude_fast_kernel(
    const float* __restrict__ sta, const float* __restrict__ src,
    const float* __restrict__ mag, const int* __restrict__ phase,
    const float* __restrict__ x_grid,
    const float* __restrict__ mag_coef, const float* __restrict__ epi_coef,
    const float* __restrict__ dep_coef,
    const float4* __restrict__ pk, const int* __restrict__ idx,
    float* __restrict__ out)
{
    const int s   = blockIdx.x;
    const int tid = threadIdx.x;

    __shared__ float s_diff[KK][3];
    __shared__ int   s_g[KK];

    if (tid < KK) {
        int g = idx[s * KK + tid];
        s_g[tid] = g;
        s_diff[tid][0] = tr1k(x_grid[g * 3 + 0]) - tr1k(src[s * 3 + 0]);
        s_diff[tid][1] = tr1k(x_grid[g * 3 + 1]) - tr1k(src[s * 3 + 1]);
        s_diff[tid][2] = tr1k(x_grid[g * 3 + 2]) - tr1k(src[s * 3 + 2]);
    }
    __syncthreads();

    const float mag_s = mag[s];
    const float srcx = src[s * 3 + 0];
    const float srcy = src[s * 3 + 1];
    const float srcz = src[s * 3 + 2];
    const float sp_mc0 = softplus(mag_coef[0]), sp_mc1 = softplus(mag_coef[1]);
    const float sp_ec0 = softplus(epi_coef[0]), sp_ec1 = softplus(epi_coef[1]);
    const float dc0 = dep_coef[0], dc1 = dep_coef[1];

    for (int i = tid; i < NSTA; i += 256) {
        float wsum = 0.0f, a = 0.0f;
#pragma unroll
        for (int k = 0; k < KK; ++k) {
            const float4 p = pk[(size_t)s_g[k] * NSTA + i];
            float t0 = s_diff[k][0] * p.x;
            float t1 = s_diff[k][1] * p.y;
            float t2 = s_diff[k][2] * p.z;
            float e  = expf(-0.5f * ((t0 * t0 + t1 * t1) + t2 * t2));
            wsum += e;
            a    += e * p.w;
        }
        if (wsum == 0.0f) wsum = 1.0f;

        const int ph = phase[i];
        float bias = a / wsum;

        float dx = srcx * 1000.0f - sta[i * 3 + 0] * 1000.0f;
        float dy = srcy * 1000.0f - sta[i * 3 + 1] * 1000.0f;
        float lz = log10f(sqrtf(dx * dx + dy * dy) + 1.0f);
        float ld = log10f(fabsf(srcz - sta[i * 3 + 2]) + 1.0f);

        float mc = (ph == 0) ? sp_mc0 : sp_mc1;
        float ec = (ph == 0) ? sp_ec0 : sp_ec1;
        float dc = (ph == 0) ? dc0 : dc1;

        out[(size_t)s * NSTA + i] = mag_s * mc - ec * lz + dc * ld + bias;
    }
}

// ---------------------------------------------------------------------------
// Fallback main kernel (direct gather) if ws_size can't hold the packed table.
// ---------------------------------------------------------------------------
__global__ __launch_bounds__(256) void magnitude_kernel(
    const float* __restrict__ sta, const float* __restrict__ src,
    const float* __restrict__ mag, const int* __restrict__ phase,
    const float* __restrict__ x_grid,
    const float* __restrict__ mag_coef, const float* __restrict__ epi_coef,
    const float* __restrict__ dep_coef,
    const float* __restrict__ coefs, const float* __restrict__ coefs_ker,
    const int* __restrict__ sta_ind, const int* __restrict__ idx,
    float* __restrict__ out)
{
    const int s   = blockIdx.x;
    const int tid = threadIdx.x;

    __shared__ float s_diff[KK][3];
    __shared__ int   s_g[KK];
    __shared__ int   s_sta[NSTA];

    if (tid < KK) {
        int g = idx[s * KK + tid];
        s_g[tid] = g;
        s_diff[tid][0] = tr1k(x_grid[g * 3 + 0]) - tr1k(src[s * 3 + 0]);
        s_diff[tid][1] = tr1k(x_grid[g * 3 + 1]) - tr1k(src[s * 3 + 1]);
        s_diff[tid][2] = tr1k(x_grid[g * 3 + 2]) - tr1k(src[s * 3 + 2]);
    }
    for (int i = tid; i < NSTA; i += 256) s_sta[i] = sta_ind[i];
    __syncthreads();

    const float mag_s = mag[s];
    const float srcx = src[s * 3 + 0];
    const float srcy = src[s * 3 + 1];
    const float srcz = src[s * 3 + 2];
    const float sp_mc0 = softplus(mag_coef[0]), sp_mc1 = softplus(mag_coef[1]);
    const float sp_ec0 = softplus(epi_coef[0]), sp_ec1 = softplus(epi_coef[1]);
    const float dc0 = dep_coef[0], dc1 = dep_coef[1];

    for (int i = tid; i < NSTA; i += 256) {
        const int st = s_sta[i];
        float wsum = 0.0f, a0 = 0.0f, a1 = 0.0f;
#pragma unroll
        for (int k = 0; k < KK; ++k) {
            const int g = s_g[k];
            const float* kp = coefs_ker + ((size_t)g * L_N + st) * 3;
            float k0 = softplus(kp[0]);
            float k1 = softplus(kp[1]);
            float k2 = softplus(kp[2]);
            float t0 = s_diff[k][0] / k0;
            float t1 = s_diff[k][1] / k1;
            float t2 = s_diff[k][2] / k2;
            float e  = expf(-0.5f * ((t0 * t0 + t1 * t1) + t2 * t2));
            const float* cp = coefs + ((size_t)g * L_N + st) * 2;
            wsum += e;
            a0 += e * cp[0];
            a1 += e * cp[1];
        }
        if (wsum == 0.0f) wsum = 1.0f;

        const int ph = phase[i];
        float bias = ((ph == 0) ? a0 : a1) / wsum;

        float dx = srcx * 1000.0f - sta[i * 3 + 0] * 1000.0f;
        float dy = srcy * 1000.0f - sta[i * 3 + 1] * 1000.0f;
        float lz = log10f(sqrtf(dx * dx + dy * dy) + 1.0f);
        float ld = log10f(fabsf(srcz - sta[i * 3 + 2]) + 1.0f);

        float mc = (ph == 0) ? sp_mc0 : sp_mc1;
        float ec = (ph == 0) ? sp_ec0 : sp_ec1;
        float dc = (ph == 0) ? dc0 : dc1;

        out[(size_t)s * NSTA + i] = mag_s * mc - ec * lz + dc * ld + bias;
    }
}

extern "C" void kernel_launch(void* const* d_in, const int* in_sizes, int n_in,
                              void* d_out, int out_size, void* d_ws, size_t ws_size,
                              hipStream_t stream) {
    const float* sta       = (const float*)d_in[0];
    const float* src       = (const float*)d_in[1];
    const float* mag       = (const float*)d_in[2];
    const int*   phase     = (const int*)d_in[3];
    const float* x_grid    = (const float*)d_in[4];
    const float* locs_ref  = (const float*)d_in[5];
    const float* mag_coef  = (const float*)d_in[6];
    const float* epi_coef  = (const float*)d_in[7];
    const float* dep_coef  = (const float*)d_in[8];
    const float* coefs     = (const float*)d_in[9];
    const float* coefs_ker = (const float*)d_in[10];
    float* out = (float*)d_out;

    const size_t pk_bytes = (size_t)G_N * NSTA * sizeof(float4);  // 64 MB
    const size_t need_fast = pk_bytes + (size_t)NSRC * KK * sizeof(int) + NSTA * sizeof(int);

    if (ws_size >= need_fast) {
        float4* ws_pk  = (float4*)d_ws;
        int* ws_idx    = (int*)((char*)d_ws + pk_bytes);
        int* ws_sta    = ws_idx + (size_t)NSRC * KK;

        hipLaunchKernelGGL(sta_ind_kernel, dim3(NSTA), dim3(64), 0, stream,
                           sta, locs_ref, ws_sta);
        hipLaunchKernelGGL(topk_kernel, dim3(NSRC), dim3(256), 0, stream,
                           src, x_grid, ws_idx);
        hipLaunchKernelGGL(pack_kernel, dim3(G_N), dim3(256), 0, stream,
                           coefs, coefs_ker, ws_sta, phase, ws_pk);
        hipLaunchKernelGGL(magnitude_fast_kernel, dim3(NSRC), dim3(256), 0, stream,
                           sta, src, mag, phase, x_grid,
                           mag_coef, epi_coef, dep_coef,
                           ws_pk, ws_idx, out);
    } else {
        int* ws_sta = (int*)d_ws;
        int* ws_idx = ws_sta + NSTA;

        hipLaunchKernelGGL(sta_ind_kernel, dim3(NSTA), dim3(64), 0, stream,
                           sta, locs_ref, ws_sta);
        hipLaunchKernelGGL(topk_kernel, dim3(NSRC), dim3(256), 0, stream,
                           src, x_grid, ws_idx);
        hipLaunchKernelGGL(magnitude_kernel, dim3(NSRC), dim3(256), 0, stream,
                           sta, src, mag, phase, x_grid,
                           mag_coef, epi_coef, dep_coef,
                           coefs, coefs_ker, ws_sta, ws_idx, out);
    }
}

// Round 3
// 202.995 us; speedup vs baseline: 1.7235x; 1.1312x over previous
//
#include <hip/hip_runtime.h>
#include <cstddef>

#define G_N   10000
#define L_N   1000
#define NSTA  400
#define NSRC  2000
#define KK    15

__device__ __forceinline__ float tr1k(float x) {
    // matches reference: _ftrns(x)/1000.0 = (x*1000.0f)/1000.0f with f32 rounding
    return (x * 1000.0f) / 1000.0f;
}

__device__ __forceinline__ float softplus(float x) {
    // jax.nn.softplus(x) = logaddexp(x, 0), stable form
    return fmaxf(x, 0.0f) + log1pf(expf(-fabsf(x)));
}

__device__ __forceinline__ bool lexless(float v1, int i1, float v2, int i2) {
    return (v1 < v2) || (v1 == v2 && i1 < i2);
}

// ---------------------------------------------------------------------------
// Kernel 1: sta_ind[i] = argmin_j ||tr(sta[i]) - tr(locs_ref[j])||^2
// one wave per station
// ---------------------------------------------------------------------------
__global__ void sta_ind_kernel(const float* __restrict__ sta,
                               const float* __restrict__ locs_ref,
                               int* __restrict__ sta_ind) {
#pragma clang fp contract(off)
    const int i    = blockIdx.x;
    const int lane = threadIdx.x;
    const float sx = tr1k(sta[i * 3 + 0]);
    const float sy = tr1k(sta[i * 3 + 1]);
    const float sz = tr1k(sta[i * 3 + 2]);
    float best = INFINITY;
    int   bidx = 0x7fffffff;
    for (int j = lane; j < L_N; j += 64) {
        float dx = sx - tr1k(locs_ref[j * 3 + 0]);
        float dy = sy - tr1k(locs_ref[j * 3 + 1]);
        float dz = sz - tr1k(locs_ref[j * 3 + 2]);
        float d  = (dx * dx + dy * dy) + dz * dz;
        if (lexless(d, j, best, bidx)) { best = d; bidx = j; }
    }
    for (int off = 1; off < 64; off <<= 1) {
        float ov = __shfl_xor(best, off);
        int   oi = __shfl_xor(bidx, off);
        if (lexless(ov, oi, best, bidx)) { best = ov; bidx = oi; }
    }
    if (lane == 0) sta_ind[i] = bidx;
}

// ---------------------------------------------------------------------------
// Kernel 2: per src s, indices of the K smallest dq[s,g], ascending by (dq,g).
// 256 threads/block; per-thread register top-K over ~40 candidates,
// per-wave 15-round lex-min extraction, then cross-wave merge in LDS.
// ---------------------------------------------------------------------------
__global__ __launch_bounds__(256) void topk_kernel(const float* __restrict__ src,
                                                   const float* __restrict__ x_grid,
                                                   int* __restrict__ idx_out) {
#pragma clang fp contract(off)
    const int s    = blockIdx.x;
    const int tid  = threadIdx.x;
    const int lane = tid & 63;
    const int wv   = tid >> 6;
    const float sx = tr1k(src[s * 3 + 0]);
    const float sy = tr1k(src[s * 3 + 1]);
    const float sz = tr1k(src[s * 3 + 2]);

    float vals[KK];
    int   ids[KK];
#pragma unroll
    for (int j = 0; j < KK; ++j) { vals[j] = INFINITY; ids[j] = 0x7fffffff; }

    for (int g = tid; g < G_N; g += 256) {
        float dx = sx - tr1k(x_grid[g * 3 + 0]);
        float dy = sy - tr1k(x_grid[g * 3 + 1]);
        float dz = sz - tr1k(x_grid[g * 3 + 2]);
        float d  = (dx * dx + dy * dy) + dz * dz;
        if (lexless(d, g, vals[KK - 1], ids[KK - 1])) {
            float cv = d; int ci = g;
#pragma unroll
            for (int j = 0; j < KK; ++j) {
                bool sw = lexless(cv, ci, vals[j], ids[j]);
                float tv = sw ? vals[j] : cv;
                int   ti = sw ? ids[j]  : ci;
                vals[j]  = sw ? cv : vals[j];
                ids[j]   = sw ? ci : ids[j];
                cv = tv; ci = ti;
            }
        }
    }

    __shared__ float l_v[4 * KK];
    __shared__ int   l_i[4 * KK];

    // per-wave: extract its sorted top-15 into LDS
    for (int r = 0; r < KK; ++r) {
        float v  = vals[0];
        int   id = ids[0];
        int   who = lane;
        for (int off = 1; off < 64; off <<= 1) {
            float ov = __shfl_xor(v, off);
            int   oi = __shfl_xor(id, off);
            int   ow = __shfl_xor(who, off);
            if (lexless(ov, oi, v, id)) { v = ov; id = oi; who = ow; }
        }
        if (lane == 0) { l_v[wv * KK + r] = v; l_i[wv * KK + r] = id; }
        if (who == lane) {
#pragma unroll
            for (int j = 0; j < KK - 1; ++j) { vals[j] = vals[j + 1]; ids[j] = ids[j + 1]; }
            vals[KK - 1] = INFINITY;
            ids[KK - 1]  = 0x7fffffff;
        }
    }
    __syncthreads();

    // wave 0: merge the 60 candidates
    if (wv == 0) {
        float v  = (lane < 4 * KK) ? l_v[lane] : INFINITY;
        int   id = (lane < 4 * KK) ? l_i[lane] : 0x7fffffff;
        for (int r = 0; r < KK; ++r) {
            float mv = v; int mi = id; int who = lane;
            for (int off = 1; off < 64; off <<= 1) {
                float ov = __shfl_xor(mv, off);
                int   oi = __shfl_xor(mi, off);
                int   ow = __shfl_xor(who, off);
                if (lexless(ov, oi, mv, mi)) { mv = ov; mi = oi; who = ow; }
            }
            if (lane == 0) idx_out[s * KK + r] = mi;
            if (who == lane) { v = INFINITY; id = 0x7fffffff; }
        }
    }
}

// ---------------------------------------------------------------------------
// used-flag helpers: only pack grid rows that some src's top-k references.
// ---------------------------------------------------------------------------
__global__ void zero_used_kernel(int* __restrict__ used) {
    int i = blockIdx.x * blockDim.x + threadIdx.x;
    if (i < G_N) used[i] = 0;
}

__global__ void mark_used_kernel(const int* __restrict__ idx,
                                 int* __restrict__ used) {
    int i = blockIdx.x * blockDim.x + threadIdx.x;
    if (i < NSRC * KK) used[idx[i]] = 1;   // benign races; deterministic result
}

// ---------------------------------------------------------------------------
// Kernel 3: pack, direct gather (no LDS, no barrier). One block per g.
// Writes float4 {1/sp(k0), 1/sp(k1), 1/sp(k2), coef_selected} at [g][i].
// ---------------------------------------------------------------------------
__global__ __launch_bounds__(256) void pack_kernel(
    const float* __restrict__ coefs, const float* __restrict__ coefs_ker,
    const int* __restrict__ sta_ind, const int* __restrict__ phase,
    const int* __restrict__ used,
    float4* __restrict__ pk)
{
    const int g = blockIdx.x;
    if (!used[g]) return;            // wave-uniform early exit
    const int tid = threadIdx.x;
    const float* __restrict__ kr = coefs_ker + (size_t)g * (L_N * 3);
    const float* __restrict__ cr = coefs     + (size_t)g * (L_N * 2);

    for (int i = tid; i < NSTA; i += 256) {
        const int st = sta_ind[i];   // coalesced
        const int ph = phase[i];     // coalesced
        float k0 = kr[st * 3 + 0];
        float k1 = kr[st * 3 + 1];
        float k2 = kr[st * 3 + 2];
        float c0 = cr[st * 2 + 0];
        float c1 = cr[st * 2 + 1];
        float rk0 = 1.0f / softplus(k0);
        float rk1 = 1.0f / softplus(k1);
        float rk2 = 1.0f / softplus(k2);
        pk[(size_t)g * NSTA + i] = make_float4(rk0, rk1, rk2, (ph == 0) ? c0 : c1);
    }
}

// ---------------------------------------------------------------------------
// Kernel 4: main fused computation, fast path. Block per src, coalesced
// float4 reads of the packed table.
// ---------------------------------------------------------------------------
__global__ __launch_bounds__(256) void magnitude_fast_kernel(
    const float* __restrict__ sta, const float* __restrict__ src,
    const float* __restrict__ mag, const int* __restrict__ phase,
    const float* __restrict__ x_grid,
    const float* __restrict__ mag_coef, const float* __restrict__ epi_coef,
    const float* __restrict__ dep_coef,
    const float4* __restrict__ pk, const int* __restrict__ idx,
    float* __restrict__ out)
{
    const int s   = blockIdx.x;
    const int tid = threadIdx.x;

    __shared__ float s_diff[KK][3];
    __shared__ int   s_g[KK];

    if (tid < KK) {
        int g = idx[s * KK + tid];
        s_g[tid] = g;
        s_diff[tid][0] = tr1k(x_grid[g * 3 + 0]) - tr1k(src[s * 3 + 0]);
        s_diff[tid][1] = tr1k(x_grid[g * 3 + 1]) - tr1k(src[s * 3 + 1]);
        s_diff[tid][2] = tr1k(x_grid[g * 3 + 2]) - tr1k(src[s * 3 + 2]);
    }
    __syncthreads();

    const float mag_s = mag[s];
    const float srcx = src[s * 3 + 0];
    const float srcy = src[s * 3 + 1];
    const float srcz = src[s * 3 + 2];
    const float sp_mc0 = softplus(mag_coef[0]), sp_mc1 = softplus(mag_coef[1]);
    const float sp_ec0 = softplus(epi_coef[0]), sp_ec1 = softplus(epi_coef[1]);
    const float dc0 = dep_coef[0], dc1 = dep_coef[1];

    for (int i = tid; i < NSTA; i += 256) {
        float wsum = 0.0f, a = 0.0f;
#pragma unroll
        for (int k = 0; k < KK; ++k) {
            const float4 p = pk[(size_t)s_g[k] * NSTA + i];
            float t0 = s_diff[k][0] * p.x;
            float t1 = s_diff[k][1] * p.y;
            float t2 = s_diff[k][2] * p.z;
            float e  = __expf(-0.5f * ((t0 * t0 + t1 * t1) + t2 * t2));
            wsum += e;
            a    += e * p.w;
        }
        if (wsum == 0.0f) wsum = 1.0f;

        const int ph = phase[i];
        float bias = a / wsum;

        float dx = srcx * 1000.0f - sta[i * 3 + 0] * 1000.0f;
        float dy = srcy * 1000.0f - sta[i * 3 + 1] * 1000.0f;
        float lz = log10f(sqrtf(dx * dx + dy * dy) + 1.0f);
        float ld = log10f(fabsf(srcz - sta[i * 3 + 2]) + 1.0f);

        float mc = (ph == 0) ? sp_mc0 : sp_mc1;
        float ec = (ph == 0) ? sp_ec0 : sp_ec1;
        float dc = (ph == 0) ? dc0 : dc1;

        out[(size_t)s * NSTA + i] = mag_s * mc - ec * lz + dc * ld + bias;
    }
}

// ---------------------------------------------------------------------------
// Fallback main kernel (direct gather) if ws_size can't hold the packed table.
// ---------------------------------------------------------------------------
__global__ __launch_bounds__(256) void magnitude_kernel(
    const float* __restrict__ sta, const float* __restrict__ src,
    const float* __restrict__ mag, const int* __restrict__ phase,
    const float* __restrict__ x_grid,
    const float* __restrict__ mag_coef, const float* __restrict__ epi_coef,
    const float* __restrict__ dep_coef,
    const float* __restrict__ coefs, const float* __restrict__ coefs_ker,
    const int* __restrict__ sta_ind, const int* __restrict__ idx,
    float* __restrict__ out)
{
    const int s   = blockIdx.x;
    const int tid = threadIdx.x;

    __shared__ float s_diff[KK][3];
    __shared__ int   s_g[KK];
    __shared__ int   s_sta[NSTA];

    if (tid < KK) {
        int g = idx[s * KK + tid];
        s_g[tid] = g;
        s_diff[tid][0] = tr1k(x_grid[g * 3 + 0]) - tr1k(src[s * 3 + 0]);
        s_diff[tid][1] = tr1k(x_grid[g * 3 + 1]) - tr1k(src[s * 3 + 1]);
        s_diff[tid][2] = tr1k(x_grid[g * 3 + 2]) - tr1k(src[s * 3 + 2]);
    }
    for (int i = tid; i < NSTA; i += 256) s_sta[i] = sta_ind[i];
    __syncthreads();

    const float mag_s = mag[s];
    const float srcx = src[s * 3 + 0];
    const float srcy = src[s * 3 + 1];
    const float srcz = src[s * 3 + 2];
    const float sp_mc0 = softplus(mag_coef[0]), sp_mc1 = softplus(mag_coef[1]);
    const float sp_ec0 = softplus(epi_coef[0]), sp_ec1 = softplus(epi_coef[1]);
    const float dc0 = dep_coef[0], dc1 = dep_coef[1];

    for (int i = tid; i < NSTA; i += 256) {
        const int st = s_sta[i];
        float wsum = 0.0f, a0 = 0.0f, a1 = 0.0f;
#pragma unroll
        for (int k = 0; k < KK; ++k) {
            const int g = s_g[k];
            const float* kp = coefs_ker + ((size_t)g * L_N + st) * 3;
            float k0 = softplus(kp[0]);
            float k1 = softplus(kp[1]);
            float k2 = softplus(kp[2]);
            float t0 = s_diff[k][0] / k0;
            float t1 = s_diff[k][1] / k1;
            float t2 = s_diff[k][2] / k2;
            float e  = expf(-0.5f * ((t0 * t0 + t1 * t1) + t2 * t2));
            const float* cp = coefs + ((size_t)g * L_N + st) * 2;
            wsum += e;
            a0 += e * cp[0];
            a1 += e * cp[1];
        }
        if (wsum == 0.0f) wsum = 1.0f;

        const int ph = phase[i];
        float bias = ((ph == 0) ? a0 : a1) / wsum;

        float dx = srcx * 1000.0f - sta[i * 3 + 0] * 1000.0f;
        float dy = srcy * 1000.0f - sta[i * 3 + 1] * 1000.0f;
        float lz = log10f(sqrtf(dx * dx + dy * dy) + 1.0f);
        float ld = log10f(fabsf(srcz - sta[i * 3 + 2]) + 1.0f);

        float mc = (ph == 0) ? sp_mc0 : sp_mc1;
        float ec = (ph == 0) ? sp_ec0 : sp_ec1;
        float dc = (ph == 0) ? dc0 : dc1;

        out[(size_t)s * NSTA + i] = mag_s * mc - ec * lz + dc * ld + bias;
    }
}

extern "C" void kernel_launch(void* const* d_in, const int* in_sizes, int n_in,
                              void* d_out, int out_size, void* d_ws, size_t ws_size,
                              hipStream_t stream) {
    const float* sta       = (const float*)d_in[0];
    const float* src       = (const float*)d_in[1];
    const float* mag       = (const float*)d_in[2];
    const int*   phase     = (const int*)d_in[3];
    const float* x_grid    = (const float*)d_in[4];
    const float* locs_ref  = (const float*)d_in[5];
    const float* mag_coef  = (const float*)d_in[6];
    const float* epi_coef  = (const float*)d_in[7];
    const float* dep_coef  = (const float*)d_in[8];
    const float* coefs     = (const float*)d_in[9];
    const float* coefs_ker = (const float*)d_in[10];
    float* out = (float*)d_out;

    const size_t pk_bytes = (size_t)G_N * NSTA * sizeof(float4);  // 64 MB
    const size_t need_fast = pk_bytes
                           + (size_t)NSRC * KK * sizeof(int)
                           + (size_t)NSTA * sizeof(int)
                           + (size_t)G_N * sizeof(int);

    if (ws_size >= need_fast) {
        float4* ws_pk  = (float4*)d_ws;
        int* ws_idx    = (int*)((char*)d_ws + pk_bytes);
        int* ws_sta    = ws_idx + (size_t)NSRC * KK;
        int* ws_used   = ws_sta + NSTA;

        hipLaunchKernelGGL(sta_ind_kernel, dim3(NSTA), dim3(64), 0, stream,
                           sta, locs_ref, ws_sta);
        hipLaunchKernelGGL(zero_used_kernel, dim3((G_N + 255) / 256), dim3(256), 0, stream,
                           ws_used);
        hipLaunchKernelGGL(topk_kernel, dim3(NSRC), dim3(256), 0, stream,
                           src, x_grid, ws_idx);
        hipLaunchKernelGGL(mark_used_kernel, dim3((NSRC * KK + 255) / 256), dim3(256), 0, stream,
                           ws_idx, ws_used);
        hipLaunchKernelGGL(pack_kernel, dim3(G_N), dim3(256), 0, stream,
                           coefs, coefs_ker, ws_sta, phase, ws_used, ws_pk);
        hipLaunchKernelGGL(magnitude_fast_kernel, dim3(NSRC), dim3(256), 0, stream,
                           sta, src, mag, phase, x_grid,
                           mag_coef, epi_coef, dep_coef,
                           ws_pk, ws_idx, out);
    } else {
        int* ws_sta = (int*)d_ws;
        int* ws_idx = ws_sta + NSTA;

        hipLaunchKernelGGL(sta_ind_kernel, dim3(NSTA), dim3(64), 0, stream,
                           sta, locs_ref, ws_sta);
        hipLaunchKernelGGL(topk_kernel, dim3(NSRC), dim3(256), 0, stream,
                           src, x_grid, ws_idx);
        hipLaunchKernelGGL(magnitude_kernel, dim3(NSRC), dim3(256), 0, stream,
                           sta, src, mag, phase, x_grid,
                           mag_coef, epi_coef, dep_coef,
                           coefs, coefs_ker, ws_sta, ws_idx, out);
    }
}

// Round 4
// 172.304 us; speedup vs baseline: 2.0305x; 1.1781x over previous
//
#include <hip/hip_runtime.h>
#include <cstddef>

#define G_N   10000
#define L_N   1000
#define NSTA  400
#define NSRC  2000
#define KK    15
#define NBIN  2048
#define CAP   1024

__device__ __forceinline__ float tr1k(float x) {
    // matches reference: _ftrns(x)/1000.0 = (x*1000.0f)/1000.0f with f32 rounding
    return (x * 1000.0f) / 1000.0f;
}

__device__ __forceinline__ float softplus(float x) {
    // jax.nn.softplus(x) = logaddexp(x, 0), stable form
    return fmaxf(x, 0.0f) + log1pf(expf(-fabsf(x)));
}

__device__ __forceinline__ bool lexless(float v1, int i1, float v2, int i2) {
    return (v1 < v2) || (v1 == v2 && i1 < i2);
}

// ---------------------------------------------------------------------------
// Kernel 1: sta_ind[i] = argmin_j ||tr(sta[i]) - tr(locs_ref[j])||^2
// one wave per station
// ---------------------------------------------------------------------------
__global__ void sta_ind_kernel(const float* __restrict__ sta,
                               const float* __restrict__ locs_ref,
                               int* __restrict__ sta_ind) {
#pragma clang fp contract(off)
    const int i    = blockIdx.x;
    const int lane = threadIdx.x;
    const float sx = tr1k(sta[i * 3 + 0]);
    const float sy = tr1k(sta[i * 3 + 1]);
    const float sz = tr1k(sta[i * 3 + 2]);
    float best = INFINITY;
    int   bidx = 0x7fffffff;
    for (int j = lane; j < L_N; j += 64) {
        float dx = sx - tr1k(locs_ref[j * 3 + 0]);
        float dy = sy - tr1k(locs_ref[j * 3 + 1]);
        float dz = sz - tr1k(locs_ref[j * 3 + 2]);
        float d  = (dx * dx + dy * dy) + dz * dz;
        if (lexless(d, j, best, bidx)) { best = d; bidx = j; }
    }
    for (int off = 1; off < 64; off <<= 1) {
        float ov = __shfl_xor(best, off);
        int   oi = __shfl_xor(bidx, off);
        if (lexless(ov, oi, best, bidx)) { best = ov; bidx = oi; }
    }
    if (lane == 0) sta_ind[i] = bidx;
}

// ---------------------------------------------------------------------------
// Kernel 2 (v2): histogram select. One block per src.
// Phase 1: all 10000 distances -> LDS + 2048-bin histogram of bits>>20
//          (monotonic key for positive floats).
// Phase 2: wave 0 prefix-scans bins, finds boundary bin B (cum count >= 15).
// Phase 3: append all g with key <= B (expected ~15-40) to candidate list.
// Phase 4: wave 0 lex-sorts candidates, writes 15 ascending (dq, g).
// Deterministic fallback (block argmin x15) if survivors > CAP.
// ---------------------------------------------------------------------------
__global__ __launch_bounds__(256) void topk_kernel(const float* __restrict__ src,
                                                   const float* __restrict__ x_grid,
                                                   int* __restrict__ idx_out) {
#pragma clang fp contract(off)
    const int s    = blockIdx.x;
    const int tid  = threadIdx.x;
    const int lane = tid & 63;
    const int wv   = tid >> 6;

    __shared__ float        s_d[G_N];
    __shared__ unsigned int s_hist[NBIN];
    __shared__ int          s_cand[CAP];
    __shared__ int          s_cnt;
    __shared__ int          s_binB;
    __shared__ int          s_nle;
    __shared__ float        s_mv[4];
    __shared__ int          s_mi[4];

    for (int b = tid; b < NBIN; b += 256) s_hist[b] = 0u;
    if (tid == 0) s_cnt = 0;
    __syncthreads();

    const float sx = tr1k(src[s * 3 + 0]);
    const float sy = tr1k(src[s * 3 + 1]);
    const float sz = tr1k(src[s * 3 + 2]);

    for (int g = tid; g < G_N; g += 256) {
        float dx = sx - tr1k(x_grid[g * 3 + 0]);
        float dy = sy - tr1k(x_grid[g * 3 + 1]);
        float dz = sz - tr1k(x_grid[g * 3 + 2]);
        float d  = (dx * dx + dy * dy) + dz * dz;
        s_d[g] = d;
        atomicAdd(&s_hist[__float_as_uint(d) >> 20], 1u);
    }
    __syncthreads();

    // wave 0: find boundary bin
    if (wv == 0) {
        const int chunk = NBIN / 64;           // 32 bins per lane
        const int base  = lane * chunk;
        unsigned int cs = 0;
        for (int b = 0; b < chunk; ++b) cs += s_hist[base + b];
        unsigned int pfx = cs;
        for (int off = 1; off < 64; off <<= 1) {
            unsigned int o = __shfl_up(pfx, off);
            if (lane >= off) pfx += o;
        }
        unsigned long long m = __ballot(pfx >= (unsigned)KK);
        int fl = __ffsll((unsigned long long)m) - 1;
        if (lane == fl) {
            unsigned int acc = pfx - cs;       // cumulative before this chunk (< KK)
            int b = base;
            for (;;) {
                acc += s_hist[b];
                if (acc >= (unsigned)KK) break;
                ++b;
            }
            s_binB = b;
            s_nle  = (int)acc;                 // count of keys <= B
        }
    }
    __syncthreads();

    const int binB = s_binB;
    const int nle  = s_nle;

    if (nle <= CAP) {
        for (int g = tid; g < G_N; g += 256) {
            if ((int)(__float_as_uint(s_d[g]) >> 20) <= binB) {
                int p = atomicAdd(&s_cnt, 1);
                s_cand[p] = g;
            }
        }
        __syncthreads();
        if (wv == 0) {
            const int n = s_cnt;
            float vals[KK];
            int   ids[KK];
#pragma unroll
            for (int j = 0; j < KK; ++j) { vals[j] = INFINITY; ids[j] = 0x7fffffff; }
            for (int c = lane; c < n; c += 64) {
                int   g = s_cand[c];
                float d = s_d[g];
                if (lexless(d, g, vals[KK - 1], ids[KK - 1])) {
                    float cv = d; int ci = g;
#pragma unroll
                    for (int j = 0; j < KK; ++j) {
                        bool sw = lexless(cv, ci, vals[j], ids[j]);
                        float tv = sw ? vals[j] : cv;
                        int   ti = sw ? ids[j]  : ci;
                        vals[j]  = sw ? cv : vals[j];
                        ids[j]   = sw ? ci : ids[j];
                        cv = tv; ci = ti;
                    }
                }
            }
            for (int r = 0; r < KK; ++r) {
                float v  = vals[0];
                int   id = ids[0];
                int   who = lane;
                for (int off = 1; off < 64; off <<= 1) {
                    float ov = __shfl_xor(v, off);
                    int   oi = __shfl_xor(id, off);
                    int   ow = __shfl_xor(who, off);
                    if (lexless(ov, oi, v, id)) { v = ov; id = oi; who = ow; }
                }
                if (lane == 0) idx_out[s * KK + r] = id;
                if (who == lane) {
#pragma unroll
                    for (int j = 0; j < KK - 1; ++j) { vals[j] = vals[j + 1]; ids[j] = ids[j + 1]; }
                    vals[KK - 1] = INFINITY;
                    ids[KK - 1]  = 0x7fffffff;
                }
            }
        }
    } else {
        // fallback: 15 rounds of block-wide lex-argmin with removal
        for (int r = 0; r < KK; ++r) {
            float v  = INFINITY;
            int   id = 0x7fffffff;
            for (int g = tid; g < G_N; g += 256) {
                float d = s_d[g];
                if (lexless(d, g, v, id)) { v = d; id = g; }
            }
            for (int off = 1; off < 64; off <<= 1) {
                float ov = __shfl_xor(v, off);
                int   oi = __shfl_xor(id, off);
                if (lexless(ov, oi, v, id)) { v = ov; id = oi; }
            }
            if (lane == 0) { s_mv[wv] = v; s_mi[wv] = id; }
            __syncthreads();
            if (tid == 0) {
                float bv = s_mv[0]; int bi = s_mi[0];
                for (int w = 1; w < 4; ++w)
                    if (lexless(s_mv[w], s_mi[w], bv, bi)) { bv = s_mv[w]; bi = s_mi[w]; }
                idx_out[s * KK + r] = bi;
                s_d[bi] = INFINITY;
            }
            __syncthreads();
        }
    }
}

// ---------------------------------------------------------------------------
// used-flag helpers: only pack grid rows that some src's top-k references.
// ---------------------------------------------------------------------------
__global__ void zero_used_kernel(int* __restrict__ used) {
    int i = blockIdx.x * blockDim.x + threadIdx.x;
    if (i < G_N) used[i] = 0;
}

__global__ void mark_used_kernel(const int* __restrict__ idx,
                                 int* __restrict__ used) {
    int i = blockIdx.x * blockDim.x + threadIdx.x;
    if (i < NSRC * KK) used[idx[i]] = 1;   // benign races; deterministic result
}

// ---------------------------------------------------------------------------
// Kernel 3: pack, direct gather (no LDS, no barrier). One block per g.
// Writes float4 {1/sp(k0), 1/sp(k1), 1/sp(k2), coef_selected} at [g][i].
// ---------------------------------------------------------------------------
__global__ __launch_bounds__(256) void pack_kernel(
    const float* __restrict__ coefs, const float* __restrict__ coefs_ker,
    const int* __restrict__ sta_ind, const int* __restrict__ phase,
    const int* __restrict__ used,
    float4* __restrict__ pk)
{
    const int g = blockIdx.x;
    if (!used[g]) return;            // wave-uniform early exit
    const int tid = threadIdx.x;
    const float* __restrict__ kr = coefs_ker + (size_t)g * (L_N * 3);
    const float* __restrict__ cr = coefs     + (size_t)g * (L_N * 2);

    for (int i = tid; i < NSTA; i += 256) {
        const int st = sta_ind[i];   // coalesced
        const int ph = phase[i];     // coalesced
        float k0 = kr[st * 3 + 0];
        float k1 = kr[st * 3 + 1];
        float k2 = kr[st * 3 + 2];
        float c0 = cr[st * 2 + 0];
        float c1 = cr[st * 2 + 1];
        float rk0 = 1.0f / softplus(k0);
        float rk1 = 1.0f / softplus(k1);
        float rk2 = 1.0f / softplus(k2);
        pk[(size_t)g * NSTA + i] = make_float4(rk0, rk1, rk2, (ph == 0) ? c0 : c1);
    }
}

// ---------------------------------------------------------------------------
// Kernel 4: main fused computation, fast path. Block per src, coalesced
// float4 reads of the packed table.
// ---------------------------------------------------------------------------
__global__ __launch_bounds__(256) void magnitude_fast_kernel(
    const float* __restrict__ sta, const float* __restrict__ src,
    const float* __restrict__ mag, const int* __restrict__ phase,
    const float* __restrict__ x_grid,
    const float* __restrict__ mag_coef, const float* __restrict__ epi_coef,
    const float* __restrict__ dep_coef,
    const float4* __restrict__ pk, const int* __restrict__ idx,
    float* __restrict__ out)
{
    const int s   = blockIdx.x;
    const int tid = threadIdx.x;

    __shared__ float s_diff[KK][3];
    __shared__ int   s_g[KK];

    if (tid < KK) {
        int g = idx[s * KK + tid];
        s_g[tid] = g;
        s_diff[tid][0] = tr1k(x_grid[g * 3 + 0]) - tr1k(src[s * 3 + 0]);
        s_diff[tid][1] = tr1k(x_grid[g * 3 + 1]) - tr1k(src[s * 3 + 1]);
        s_diff[tid][2] = tr1k(x_grid[g * 3 + 2]) - tr1k(src[s * 3 + 2]);
    }
    __syncthreads();

    const float mag_s = mag[s];
    const float srcx = src[s * 3 + 0];
    const float srcy = src[s * 3 + 1];
    const float srcz = src[s * 3 + 2];
    const float sp_mc0 = softplus(mag_coef[0]), sp_mc1 = softplus(mag_coef[1]);
    const float sp_ec0 = softplus(epi_coef[0]), sp_ec1 = softplus(epi_coef[1]);
    const float dc0 = dep_coef[0], dc1 = dep_coef[1];

    for (int i = tid; i < NSTA; i += 256) {
        float wsum = 0.0f, a = 0.0f;
#pragma unroll
        for (int k = 0; k < KK; ++k) {
            const float4 p = pk[(size_t)s_g[k] * NSTA + i];
            float t0 = s_diff[k][0] * p.x;
            float t1 = s_diff[k][1] * p.y;
            float t2 = s_diff[k][2] * p.z;
            float e  = __expf(-0.5f * ((t0 * t0 + t1 * t1) + t2 * t2));
            wsum += e;
            a    += e * p.w;
        }
        if (wsum == 0.0f) wsum = 1.0f;

        const int ph = phase[i];
        float bias = a / wsum;

        float dx = srcx * 1000.0f - sta[i * 3 + 0] * 1000.0f;
        float dy = srcy * 1000.0f - sta[i * 3 + 1] * 1000.0f;
        float lz = log10f(sqrtf(dx * dx + dy * dy) + 1.0f);
        float ld = log10f(fabsf(srcz - sta[i * 3 + 2]) + 1.0f);

        float mc = (ph == 0) ? sp_mc0 : sp_mc1;
        float ec = (ph == 0) ? sp_ec0 : sp_ec1;
        float dc = (ph == 0) ? dc0 : dc1;

        out[(size_t)s * NSTA + i] = mag_s * mc - ec * lz + dc * ld + bias;
    }
}

// ---------------------------------------------------------------------------
// Fallback main kernel (direct gather) if ws_size can't hold the packed table.
// ---------------------------------------------------------------------------
__global__ __launch_bounds__(256) void magnitude_kernel(
    const float* __restrict__ sta, const float* __restrict__ src,
    const float* __restrict__ mag, const int* __restrict__ phase,
    const float* __restrict__ x_grid,
    const float* __restrict__ mag_coef, const float* __restrict__ epi_coef,
    const float* __restrict__ dep_coef,
    const float* __restrict__ coefs, const float* __restrict__ coefs_ker,
    const int* __restrict__ sta_ind, const int* __restrict__ idx,
    float* __restrict__ out)
{
    const int s   = blockIdx.x;
    const int tid = threadIdx.x;

    __shared__ float s_diff[KK][3];
    __shared__ int   s_g[KK];
    __shared__ int   s_sta[NSTA];

    if (tid < KK) {
        int g = idx[s * KK + tid];
        s_g[tid] = g;
        s_diff[tid][0] = tr1k(x_grid[g * 3 + 0]) - tr1k(src[s * 3 + 0]);
        s_diff[tid][1] = tr1k(x_grid[g * 3 + 1]) - tr1k(src[s * 3 + 1]);
        s_diff[tid][2] = tr1k(x_grid[g * 3 + 2]) - tr1k(src[s * 3 + 2]);
    }
    for (int i = tid; i < NSTA; i += 256) s_sta[i] = sta_ind[i];
    __syncthreads();

    const float mag_s = mag[s];
    const float srcx = src[s * 3 + 0];
    const float srcy = src[s * 3 + 1];
    const float srcz = src[s * 3 + 2];
    const float sp_mc0 = softplus(mag_coef[0]), sp_mc1 = softplus(mag_coef[1]);
    const float sp_ec0 = softplus(epi_coef[0]), sp_ec1 = softplus(epi_coef[1]);
    const float dc0 = dep_coef[0], dc1 = dep_coef[1];

    for (int i = tid; i < NSTA; i += 256) {
        const int st = s_sta[i];
        float wsum = 0.0f, a0 = 0.0f, a1 = 0.0f;
#pragma unroll
        for (int k = 0; k < KK; ++k) {
            const int g = s_g[k];
            const float* kp = coefs_ker + ((size_t)g * L_N + st) * 3;
            float k0 = softplus(kp[0]);
            float k1 = softplus(kp[1]);
            float k2 = softplus(kp[2]);
            float t0 = s_diff[k][0] / k0;
            float t1 = s_diff[k][1] / k1;
            float t2 = s_diff[k][2] / k2;
            float e  = expf(-0.5f * ((t0 * t0 + t1 * t1) + t2 * t2));
            const float* cp = coefs + ((size_t)g * L_N + st) * 2;
            wsum += e;
            a0 += e * cp[0];
            a1 += e * cp[1];
        }
        if (wsum == 0.0f) wsum = 1.0f;

        const int ph = phase[i];
        float bias = ((ph == 0) ? a0 : a1) / wsum;

        float dx = srcx * 1000.0f - sta[i * 3 + 0] * 1000.0f;
        float dy = srcy * 1000.0f - sta[i * 3 + 1] * 1000.0f;
        float lz = log10f(sqrtf(dx * dx + dy * dy) + 1.0f);
        float ld = log10f(fabsf(srcz - sta[i * 3 + 2]) + 1.0f);

        float mc = (ph == 0) ? sp_mc0 : sp_mc1;
        float ec = (ph == 0) ? sp_ec0 : sp_ec1;
        float dc = (ph == 0) ? dc0 : dc1;

        out[(size_t)s * NSTA + i] = mag_s * mc - ec * lz + dc * ld + bias;
    }
}

extern "C" void kernel_launch(void* const* d_in, const int* in_sizes, int n_in,
                              void* d_out, int out_size, void* d_ws, size_t ws_size,
                              hipStream_t stream) {
    const float* sta       = (const float*)d_in[0];
    const float* src       = (const float*)d_in[1];
    const float* mag       = (const float*)d_in[2];
    const int*   phase     = (const int*)d_in[3];
    const float* x_grid    = (const float*)d_in[4];
    const float* locs_ref  = (const float*)d_in[5];
    const float* mag_coef  = (const float*)d_in[6];
    const float* epi_coef  = (const float*)d_in[7];
    const float* dep_coef  = (const float*)d_in[8];
    const float* coefs     = (const float*)d_in[9];
    const float* coefs_ker = (const float*)d_in[10];
    float* out = (float*)d_out;

    const size_t pk_bytes = (size_t)G_N * NSTA * sizeof(float4);  // 64 MB
    const size_t need_fast = pk_bytes
                           + (size_t)NSRC * KK * sizeof(int)
                           + (size_t)NSTA * sizeof(int)
                           + (size_t)G_N * sizeof(int);

    if (ws_size >= need_fast) {
        float4* ws_pk  = (float4*)d_ws;
        int* ws_idx    = (int*)((char*)d_ws + pk_bytes);
        int* ws_sta    = ws_idx + (size_t)NSRC * KK;
        int* ws_used   = ws_sta + NSTA;

        hipLaunchKernelGGL(sta_ind_kernel, dim3(NSTA), dim3(64), 0, stream,
                           sta, locs_ref, ws_sta);
        hipLaunchKernelGGL(zero_used_kernel, dim3((G_N + 255) / 256), dim3(256), 0, stream,
                           ws_used);
        hipLaunchKernelGGL(topk_kernel, dim3(NSRC), dim3(256), 0, stream,
                           src, x_grid, ws_idx);
        hipLaunchKernelGGL(mark_used_kernel, dim3((NSRC * KK + 255) / 256), dim3(256), 0, stream,
                           ws_idx, ws_used);
        hipLaunchKernelGGL(pack_kernel, dim3(G_N), dim3(256), 0, stream,
                           coefs, coefs_ker, ws_sta, phase, ws_used, ws_pk);
        hipLaunchKernelGGL(magnitude_fast_kernel, dim3(NSRC), dim3(256), 0, stream,
                           sta, src, mag, phase, x_grid,
                           mag_coef, epi_coef, dep_coef,
                           ws_pk, ws_idx, out);
    } else {
        int* ws_sta = (int*)d_ws;
        int* ws_idx = ws_sta + NSTA;

        hipLaunchKernelGGL(sta_ind_kernel, dim3(NSTA), dim3(64), 0, stream,
                           sta, locs_ref, ws_sta);
        hipLaunchKernelGGL(topk_kernel, dim3(NSRC), dim3(256), 0, stream,
                           src, x_grid, ws_idx);
        hipLaunchKernelGGL(magnitude_kernel, dim3(NSRC), dim3(256), 0, stream,
                           sta, src, mag, phase, x_grid,
                           mag_coef, epi_coef, dep_coef,
                           coefs, coefs_ker, ws_sta, ws_idx, out);
    }
}